// Round 6
// baseline (126.948 us; speedup 1.0000x reference)
//
#include <hip/hip_runtime.h>

#define TG_D    4096
#define TG_BLK  256
#define TG_CAP  832
#define TG_ROWS 4
#define TG_T0   1.00f
// bin-floor guard (float-bits domain): threshold bin must be >= 0x3F58,
// i.e. g* >= 0.84375 > gelu(1.0) = 0.841345 -> no non-candidate can qualify.
#define TG_BING 0x3F58u

typedef float v4f __attribute__((ext_vector_type(4)));

__device__ __forceinline__ unsigned tg_key(float f) {   // slow path only
  unsigned b = __float_as_uint(f);
  return (b & 0x80000000u) ? ~b : (b | 0x80000000u);
}
__device__ __forceinline__ unsigned tg_dec(unsigned k) {
  return (k & 0x80000000u) ? (k & 0x7FFFFFFFu) : ~k;
}

// Bit-exact replication of jax.nn.gelu(approximate=False) (verified r1-r5:
// absmax == bf16 storage ulp across all rows). Do not touch.
__device__ __forceinline__ float tg_gelu(float x) {
#pragma clang fp contract(off)
  float d  = x / 0x1.6a09e6p+0f;            // IEEE divide by float32(sqrt(2))
  float xc = fmaxf(fminf(d, 4.0f), -4.0f);
  float x2 = xc * xc;
  float p = -2.72614225801306e-10f;
  p = __builtin_fmaf(p, x2,  2.77068142495902e-08f);
  p = __builtin_fmaf(p, x2, -2.10102402082508e-06f);
  p = __builtin_fmaf(p, x2, -5.69250639462346e-05f);
  p = __builtin_fmaf(p, x2, -7.34990630326855e-04f);
  p = __builtin_fmaf(p, x2, -2.95459980854025e-03f);
  p = __builtin_fmaf(p, x2, -1.60960333262415e-02f);
  float q = -1.45660718464996e-05f;
  q = __builtin_fmaf(q, x2, -2.13374055278905e-04f);
  q = __builtin_fmaf(q, x2, -1.68282697438203e-03f);
  q = __builtin_fmaf(q, x2, -7.37332916720468e-03f);
  q = __builtin_fmaf(q, x2, -1.42647390514189e-02f);
  float num = xc * p;
  float e   = num / q;                      // IEEE divide
  float s   = e + 1.0f;
  float m   = x * s;
  return m * 0.5f;
}

// slow-path pick: sel[0]=byte, sel[1]=strictly-greater, sel[2]=bin count.
__device__ __forceinline__ void tg_pick_byte(unsigned (*h)[256], unsigned* wtot,
                                             unsigned* sel, unsigned kRem,
                                             int tid, int lane, int wv) {
  __syncthreads();
  unsigned cb = h[0][tid] + h[1][tid] + h[2][tid] + h[3][tid];
  unsigned v = cb;
#pragma unroll
  for (int d = 1; d < 64; d <<= 1) {
    unsigned o = __shfl_down(v, d, 64);
    v += (lane + d < 64) ? o : 0u;
  }
  if (lane == 0) wtot[wv] = v;
  __syncthreads();
  unsigned hi = 0;
#pragma unroll
  for (int w = 0; w < 4; ++w)
    if (w > wv) hi += wtot[w];
  unsigned sGE = v + hi, sGT = sGE - cb;
  if (sGE >= kRem && sGT < kRem) { sel[0] = (unsigned)tid; sel[1] = sGT; sel[2] = cb; }
  __syncthreads();
}

__global__ __launch_bounds__(TG_BLK) void topk_gelu_kernel(
    const float* __restrict__ x, const int* __restrict__ kptr,
    float* __restrict__ out, int nrows) {
  __shared__ float          cx[TG_CAP];      // candidate x (thread-major)
  __shared__ unsigned       ckey[TG_CAP];    // candidate gelu float-bits
  __shared__ unsigned short cidx[TG_CAP];    // candidate row position
  __shared__ unsigned       hist[4][256];
  __shared__ unsigned       skey[64];
  __shared__ unsigned short scidx[64];
  __shared__ unsigned short scpos[64];
  __shared__ unsigned       tieMask[128];
  __shared__ unsigned       wtot[4];
  __shared__ unsigned       sel[3];
  __shared__ unsigned       cnt2, mCnt;

  const int tid = threadIdx.x, lane = tid & 63, wv = tid >> 6;
  const unsigned k = (unsigned)(*kptr);
  const long row0 = (long)blockIdx.x * TG_ROWS;

  // ---- preload first row into registers ----
  float xv[16], xn[16];
  {
    const float* xr = x + (size_t)row0 * TG_D;
#pragma unroll
    for (int c = 0; c < 4; ++c) {
      float4 v = reinterpret_cast<const float4*>(xr)[tid + c * TG_BLK];
      xv[4*c+0] = v.x; xv[4*c+1] = v.y; xv[4*c+2] = v.z; xv[4*c+3] = v.w;
    }
  }

  for (int r = 0; r < TG_ROWS; ++r) {
    const long row = row0 + r;
    if (row >= nrows) break;                         // block-uniform
    float* outr = out + (size_t)row * TG_D;
    const bool havePrefetch = (r + 1 < TG_ROWS) && (row + 1 < nrows);

    __syncthreads();                                 // B0: prev-row LDS readers done
    hist[0][tid] = 0; hist[1][tid] = 0; hist[2][tid] = 0; hist[3][tid] = 0;
    if (tid == 0) { cnt2 = 0; mCnt = 0; sel[0] = 0; sel[1] = 0; sel[2] = 0; }

    // ---- candidate mask + block scan ----
    unsigned candMask = 0;
#pragma unroll
    for (int e = 0; e < 16; ++e)
      if (xv[e] >= TG_T0) candMask |= (1u << e);
    const unsigned cnt = (unsigned)__popc(candMask);
    unsigned inc = cnt;
#pragma unroll
    for (int d = 1; d < 64; d <<= 1) {
      unsigned o = __shfl_up(inc, d, 64);
      if (lane >= d) inc += o;
    }
    if (lane == 63) wtot[wv] = inc;
    __syncthreads();                                 // B1
    unsigned base = inc - cnt;
#pragma unroll
    for (int w = 0; w < 4; ++w) if (w < wv) base += wtot[w];
    const unsigned n0 = wtot[0] + wtot[1] + wtot[2] + wtot[3];
    const unsigned nC = n0 < (unsigned)TG_CAP ? n0 : (unsigned)TG_CAP;

    if (n0 <= (unsigned)TG_CAP) {
      unsigned p = base;
#pragma unroll
      for (int e = 0; e < 16; ++e)
        if (candMask & (1u << e)) {
          cx[p]   = xv[e];
          cidx[p] = (unsigned short)((tid + (e >> 2) * TG_BLK) * 4 + (e & 3));
          ++p;
        }
    }

    // ---- issue next-row loads; consumed only at the row swap below ----
    if (havePrefetch) {
      const float* xrn = x + (size_t)(row + 1) * TG_D;
#pragma unroll
      for (int c = 0; c < 4; ++c) {
        float4 v = reinterpret_cast<const float4*>(xrn)[tid + c * TG_BLK];
        xn[4*c+0] = v.x; xn[4*c+1] = v.y; xn[4*c+2] = v.z; xn[4*c+3] = v.w;
      }
    }
    __syncthreads();                                 // B2

    // ---- dense gelu (float-bits domain) + byte1 hist + auto-keep count ----
    unsigned myc2 = 0;
    for (unsigned i = tid; i < nC; i += TG_BLK) {
      unsigned gb = __float_as_uint(tg_gelu(cx[i]));  // all positive here
      ckey[i] = gb;
      if (gb >= 0x40000000u) ++myc2;                  // g >= 2.0: auto-keep
      else atomicAdd(&hist[wv][(gb >> 16) & 255], 1u);
    }
#pragma unroll
    for (int d = 1; d < 64; d <<= 1) {
      unsigned o = __shfl_down(myc2, d, 64);
      myc2 += (lane + d < 64) ? o : 0u;
    }
    if (lane == 0 && myc2) atomicAdd(&cnt2, myc2);
    __syncthreads();                                 // B3

    // ---- single pick over bits[23:16] ----
    const unsigned c2v  = cnt2;
    const unsigned kRem = k - c2v;                   // underflow -> slow via c2v>=k
    unsigned cb = hist[0][tid] + hist[1][tid] + hist[2][tid] + hist[3][tid];
    unsigned v = cb;
#pragma unroll
    for (int d = 1; d < 64; d <<= 1) {
      unsigned o = __shfl_down(v, d, 64);
      v += (lane + d < 64) ? o : 0u;
    }
    if (lane == 0) wtot[wv] = v;
    __syncthreads();                                 // B4
    unsigned hi = 0;
#pragma unroll
    for (int w = 0; w < 4; ++w) if (w > wv) hi += wtot[w];
    {
      unsigned sGE = v + hi, sGT = sGE - cb;
      if (sGE >= kRem && sGT < kRem) { sel[0] = (unsigned)tid; sel[1] = sGT; sel[2] = cb; }
    }
    __syncthreads();                                 // B5

    const unsigned bin   = 0x3F00u | sel[0];         // full bits[31:16] of bin
    const unsigned kRem2 = kRem - sel[1];
    const unsigned m     = sel[2];
    const bool slow = (n0 > (unsigned)TG_CAP) || (n0 < k + 32u) || (c2v >= k) ||
                      (bin < TG_BING) || (m > 64u) || (kRem2 == 0u) || (kRem2 > m);

    if (slow) {
      // ---- general path (proven r3-r5): full-row keyed radix + tie bitmap ----
      unsigned gk[16];
#pragma unroll
      for (int e = 0; e < 16; ++e) gk[e] = tg_key(tg_gelu(xv[e]));
      unsigned prefix = 0, kRemS = k;
#pragma unroll
      for (int ps = 0; ps < 4; ++ps) {
        const int shift = 24 - 8 * ps;
        __syncthreads();
        hist[0][tid] = 0; hist[1][tid] = 0; hist[2][tid] = 0; hist[3][tid] = 0;
        __syncthreads();
        const unsigned pmask = ps ? (0xFFFFFFFFu << (shift + 8)) : 0u;
#pragma unroll
        for (int e = 0; e < 16; ++e)
          if ((gk[e] & pmask) == prefix) atomicAdd(&hist[wv][(gk[e] >> shift) & 255], 1u);
        tg_pick_byte(hist, wtot, sel, kRemS, tid, lane, wv);
        prefix |= sel[0] << shift;
        kRemS  -= sel[1];
      }
      const unsigned Tg = prefix, kRemF = kRemS, cntEq = sel[2];
      const bool needTie = (cntEq != kRemF);
      if (needTie) {
        if (tid < 128) tieMask[tid] = 0;
        __syncthreads();
#pragma unroll
        for (int e = 0; e < 16; ++e)
          if (gk[e] == Tg) {
            unsigned s = (unsigned)((tid + (e >> 2) * TG_BLK) * 4 + (e & 3));
            atomicOr(&tieMask[s >> 5], 1u << (s & 31));
          }
        __syncthreads();
      }
#pragma unroll
      for (int c = 0; c < 4; ++c) {
        float rr[4];
#pragma unroll
        for (int j = 0; j < 4; ++j) {
          const int e = 4 * c + j;
          unsigned kk = gk[e];
          bool keep = kk > Tg;
          if (!keep && kk == Tg) {
            if (!needTie) keep = true;
            else {
              unsigned s = (unsigned)((tid + c * TG_BLK) * 4 + j);
              unsigned rank = __popc(tieMask[s >> 5] & ((1u << (s & 31)) - 1u));
              for (unsigned w = 0; w < (s >> 5); ++w) rank += __popc(tieMask[w]);
              keep = rank < kRemF;
            }
          }
          rr[j] = keep ? __uint_as_float(tg_dec(kk)) : 0.0f;
        }
        v4f o4 = { rr[0], rr[1], rr[2], rr[3] };
        __builtin_nontemporal_store(o4, reinterpret_cast<v4f*>(outr) + tid + c * TG_BLK);
      }
    } else {
      // ---- gather boundary-bin survivors (~6 expected, guarded <= 64) ----
      for (unsigned i = tid; i < n0; i += TG_BLK) {
        unsigned gb = ckey[i];
        if ((gb >> 16) == bin) {
          unsigned p = atomicAdd(&mCnt, 1u);
          if (p < 64u) { skey[p] = gb; scidx[p] = cidx[i]; scpos[p] = (unsigned short)i; }
        }
      }
      __syncthreads();                               // B6

      // ---- wave 0: rank survivors (g desc, index asc), verdict into ckey ----
      if (wv == 0) {
        unsigned myk = (lane < (int)m) ? skey[lane] : 0u;
        unsigned myi = (lane < (int)m) ? (unsigned)scidx[lane] : 0xFFFFu;
        unsigned gt = 0, tr = 0;
        for (unsigned j = 0; j < m; ++j) {
          unsigned kj = __shfl(myk, (int)j, 64);
          unsigned ij = __shfl(myi, (int)j, 64);
          gt += (kj > myk) ? 1u : 0u;
          tr += (kj == myk && ij < myi) ? 1u : 0u;
        }
        if (lane < (int)m) ckey[scpos[lane]] = ((gt + tr) < kRem2) ? myk : 0u;
      }
      __syncthreads();                               // B7

      // ---- per-thread verdict (sequential ckey reads) + nontemporal store ----
      const unsigned thr = bin << 16;
      unsigned p = base;
#pragma unroll
      for (int c = 0; c < 4; ++c) {
        float rr[4];
#pragma unroll
        for (int j = 0; j < 4; ++j) {
          const int e = 4 * c + j;
          float ov = 0.0f;
          if (candMask & (1u << e)) {
            unsigned gb = ckey[p++];
            if (gb >= thr) ov = __uint_as_float(gb);
          }
          rr[j] = ov;
        }
        v4f o4 = { rr[0], rr[1], rr[2], rr[3] };
        __builtin_nontemporal_store(o4, reinterpret_cast<v4f*>(outr) + tid + c * TG_BLK);
      }
    }

    // ---- row swap: consume prefetched registers ----
    if (havePrefetch) {
#pragma unroll
      for (int e = 0; e < 16; ++e) xv[e] = xn[e];
    }
  }
}

extern "C" void kernel_launch(void* const* d_in, const int* in_sizes, int n_in,
                              void* d_out, int out_size, void* d_ws, size_t ws_size,
                              hipStream_t stream) {
  const float* x = (const float*)d_in[0];
  const int* kp  = (const int*)d_in[1];
  float* out     = (float*)d_out;
  int rows = in_sizes[0] / TG_D;
  int blocks = (rows + TG_ROWS - 1) / TG_ROWS;
  topk_gelu_kernel<<<blocks, TG_BLK, 0, stream>>>(x, kp, out, rows);
}

// Round 7
// 86.270 us; speedup vs baseline: 1.4715x; 1.4715x over previous
//
#include <hip/hip_runtime.h>

#define TG_D    4096
#define TG_BLK  256
#define TG_CAP  832
#define TG_T0   1.00f
// bin-floor guard (float-bits domain): threshold bin must be >= 0x3F58,
// i.e. g* >= 0.84375 > gelu(1.0) = 0.841345 -> no non-candidate can qualify.
#define TG_BING 0x3F58u

typedef float v4f __attribute__((ext_vector_type(4)));
typedef float v2f __attribute__((ext_vector_type(2)));

__device__ __forceinline__ unsigned tg_key(float f) {   // slow path only
  unsigned b = __float_as_uint(f);
  return (b & 0x80000000u) ? ~b : (b | 0x80000000u);
}
__device__ __forceinline__ unsigned tg_dec(unsigned k) {
  return (k & 0x80000000u) ? (k & 0x7FFFFFFFu) : ~k;
}

// Bit-exact replication of jax.nn.gelu(approximate=False) (verified r1-r6:
// absmax == bf16 storage ulp across all rows). Do not touch semantics.
__device__ __forceinline__ float tg_gelu(float x) {
#pragma clang fp contract(off)
  float d  = x / 0x1.6a09e6p+0f;            // IEEE divide by float32(sqrt(2))
  float xc = fmaxf(fminf(d, 4.0f), -4.0f);
  float x2 = xc * xc;
  float p = -2.72614225801306e-10f;
  p = __builtin_fmaf(p, x2,  2.77068142495902e-08f);
  p = __builtin_fmaf(p, x2, -2.10102402082508e-06f);
  p = __builtin_fmaf(p, x2, -5.69250639462346e-05f);
  p = __builtin_fmaf(p, x2, -7.34990630326855e-04f);
  p = __builtin_fmaf(p, x2, -2.95459980854025e-03f);
  p = __builtin_fmaf(p, x2, -1.60960333262415e-02f);
  float q = -1.45660718464996e-05f;
  q = __builtin_fmaf(q, x2, -2.13374055278905e-04f);
  q = __builtin_fmaf(q, x2, -1.68282697438203e-03f);
  q = __builtin_fmaf(q, x2, -7.37332916720468e-03f);
  q = __builtin_fmaf(q, x2, -1.42647390514189e-02f);
  float num = xc * p;
  float e   = num / q;                      // IEEE divide
  float s   = e + 1.0f;
  float m   = x * s;
  return m * 0.5f;
}

// Packed 2-wide gelu: identical per-component IEEE ops (pk-FMA = 2x IEEE FMA,
// divides scalar per component) -> bit-identical to tg_gelu on each lane-pair.
__device__ __forceinline__ v2f tg_gelu2(v2f x) {
#pragma clang fp contract(off)
  v2f d;
  d.x = x.x / 0x1.6a09e6p+0f;
  d.y = x.y / 0x1.6a09e6p+0f;
  v2f xc = __builtin_elementwise_max(
               __builtin_elementwise_min(d, (v2f)(4.0f)), (v2f)(-4.0f));
  v2f x2 = xc * xc;
  v2f p = (v2f)(-2.72614225801306e-10f);
  p = __builtin_elementwise_fma(p, x2, (v2f)( 2.77068142495902e-08f));
  p = __builtin_elementwise_fma(p, x2, (v2f)(-2.10102402082508e-06f));
  p = __builtin_elementwise_fma(p, x2, (v2f)(-5.69250639462346e-05f));
  p = __builtin_elementwise_fma(p, x2, (v2f)(-7.34990630326855e-04f));
  p = __builtin_elementwise_fma(p, x2, (v2f)(-2.95459980854025e-03f));
  p = __builtin_elementwise_fma(p, x2, (v2f)(-1.60960333262415e-02f));
  v2f q = (v2f)(-1.45660718464996e-05f);
  q = __builtin_elementwise_fma(q, x2, (v2f)(-2.13374055278905e-04f));
  q = __builtin_elementwise_fma(q, x2, (v2f)(-1.68282697438203e-03f));
  q = __builtin_elementwise_fma(q, x2, (v2f)(-7.37332916720468e-03f));
  q = __builtin_elementwise_fma(q, x2, (v2f)(-1.42647390514189e-02f));
  v2f num = xc * p;
  v2f e;
  e.x = num.x / q.x;
  e.y = num.y / q.y;
  v2f s = e + (v2f)(1.0f);
  v2f m = x * s;
  return m * (v2f)(0.5f);
}

// slow-path pick: sel[0]=byte, sel[1]=strictly-greater, sel[2]=bin count.
__device__ __forceinline__ void tg_pick_byte(unsigned (*h)[256], unsigned* wtot,
                                             unsigned* sel, unsigned kRem,
                                             int tid, int lane, int wv) {
  __syncthreads();
  unsigned cb = h[0][tid] + h[1][tid] + h[2][tid] + h[3][tid];
  unsigned v = cb;
#pragma unroll
  for (int d = 1; d < 64; d <<= 1) {
    unsigned o = __shfl_down(v, d, 64);
    v += (lane + d < 64) ? o : 0u;
  }
  if (lane == 0) wtot[wv] = v;
  __syncthreads();
  unsigned hi = 0;
#pragma unroll
  for (int w = 0; w < 4; ++w)
    if (w > wv) hi += wtot[w];
  unsigned sGE = v + hi, sGT = sGE - cb;
  if (sGE >= kRem && sGT < kRem) { sel[0] = (unsigned)tid; sel[1] = sGT; sel[2] = cb; }
  __syncthreads();
}

__global__ __launch_bounds__(TG_BLK) void topk_gelu_kernel(
    const float* __restrict__ x, const int* __restrict__ kptr,
    float* __restrict__ out) {
  __shared__ float          cx[TG_CAP];      // candidate x (wave-arrival order)
  __shared__ unsigned       ckey[TG_CAP];    // candidate gelu float-bits
  __shared__ unsigned short cidx[TG_CAP];    // candidate row position
  __shared__ alignas(16) unsigned hist[4][256];
  __shared__ unsigned       qtot[4];         // per-64-bin-quadrant totals
  __shared__ unsigned       skey[64];
  __shared__ unsigned short scidx[64];
  __shared__ unsigned short scpos[64];
  __shared__ unsigned       tieMask[128];
  __shared__ unsigned       wtot[4];         // slow path only
  __shared__ unsigned       sel[3];
  __shared__ unsigned       cnt2, mCnt, nCand;

  const int tid = threadIdx.x, lane = tid & 63, wv = tid >> 6;
  const unsigned k = (unsigned)(*kptr);
  const float* xr   = x   + (size_t)blockIdx.x * TG_D;
  float*       outr = out + (size_t)blockIdx.x * TG_D;

  // ---- LDS init + cheap ordering barrier (before the long loads) ----
  {
    uint4 z4; z4.x = 0; z4.y = 0; z4.z = 0; z4.w = 0;
    reinterpret_cast<uint4*>(hist)[tid] = z4;
  }
  if (tid < 4) qtot[tid] = 0;
  if (tid == 0) { cnt2 = 0; mCnt = 0; nCand = 0; sel[0] = 0; sel[1] = 0; sel[2] = 0; }
  __syncthreads();                                   // B0 (init only; cheap)

  // ---- coalesced load, elements stay in VGPRs ----
  float xv[16];
#pragma unroll
  for (int c = 0; c < 4; ++c) {
    float4 v = reinterpret_cast<const float4*>(xr)[tid + c * TG_BLK];
    xv[4*c+0] = v.x; xv[4*c+1] = v.y; xv[4*c+2] = v.z; xv[4*c+3] = v.w;
  }

  // ---- candidate mask + intra-wave scan; wave base via one atomic ----
  unsigned candMask = 0;
#pragma unroll
  for (int e = 0; e < 16; ++e)
    if (xv[e] >= TG_T0) candMask |= (1u << e);
  const unsigned cnt = (unsigned)__popc(candMask);
  unsigned inc = cnt;
#pragma unroll
  for (int d = 1; d < 64; d <<= 1) {
    unsigned o = __shfl_up(inc, d, 64);
    if (lane >= d) inc += o;
  }
  unsigned wb = 0;
  if (lane == 63) wb = atomicAdd(&nCand, inc);       // inc@lane63 == wave total
  wb = __shfl(wb, 63, 64);
  const unsigned base = wb + inc - cnt;

  // ---- compact (per-candidate bounds guard) ----
  {
    unsigned p = base;
#pragma unroll
    for (int e = 0; e < 16; ++e)
      if (candMask & (1u << e)) {
        if (p < (unsigned)TG_CAP) {
          cx[p]   = xv[e];
          cidx[p] = (unsigned short)((tid + (e >> 2) * TG_BLK) * 4 + (e & 3));
        }
        ++p;
      }
  }
  __syncthreads();                                   // B1
  const unsigned n0 = nCand;
  const unsigned nC = n0 < (unsigned)TG_CAP ? n0 : (unsigned)TG_CAP;

  // ---- dense packed gelu + byte1 hist + quadrant totals + auto-keep ----
  unsigned myc2 = 0;
  const unsigned nPair = nC & ~1u;
  for (unsigned i = 2 * tid; i < nPair; i += 2 * TG_BLK) {
    v2f xx = *reinterpret_cast<const v2f*>(&cx[i]);
    v2f g2 = tg_gelu2(xx);
    unsigned gb0 = __float_as_uint(g2.x);
    unsigned gb1 = __float_as_uint(g2.y);
    ckey[i]     = gb0;
    ckey[i + 1] = gb1;
    if (gb0 >= 0x40000000u) ++myc2;
    else { atomicAdd(&hist[wv][(gb0 >> 16) & 255], 1u);
           atomicAdd(&qtot[(gb0 >> 22) & 3], 1u); }
    if (gb1 >= 0x40000000u) ++myc2;
    else { atomicAdd(&hist[wv][(gb1 >> 16) & 255], 1u);
           atomicAdd(&qtot[(gb1 >> 22) & 3], 1u); }
  }
  if ((nC & 1u) && tid == 0) {                       // odd tail
    unsigned gb = __float_as_uint(tg_gelu(cx[nC - 1]));
    ckey[nC - 1] = gb;
    if (gb >= 0x40000000u) ++myc2;
    else { atomicAdd(&hist[0][(gb >> 16) & 255], 1u);
           atomicAdd(&qtot[(gb >> 22) & 3], 1u); }
  }
#pragma unroll
  for (int d = 1; d < 64; d <<= 1) {
    unsigned o = __shfl_down(myc2, d, 64);
    myc2 += (lane + d < 64) ? o : 0u;
  }
  if (lane == 0 && myc2) atomicAdd(&cnt2, myc2);
  __syncthreads();                                   // B2

  // ---- single pick over bits[23:16]; cross-wave suffix from qtot ----
  const unsigned c2v  = cnt2;
  const unsigned kRem = k - c2v;                     // underflow -> no crossing
  unsigned cb = hist[0][tid] + hist[1][tid] + hist[2][tid] + hist[3][tid];
  unsigned v = cb;
#pragma unroll
  for (int d = 1; d < 64; d <<= 1) {
    unsigned o = __shfl_down(v, d, 64);
    v += (lane + d < 64) ? o : 0u;
  }
  unsigned hi = 0;
#pragma unroll
  for (int qq = 0; qq < 4; ++qq)
    if (qq > wv) hi += qtot[qq];
  {
    unsigned sGE = v + hi, sGT = sGE - cb;
    if (sGE >= kRem && sGT < kRem) { sel[0] = (unsigned)tid; sel[1] = sGT; sel[2] = cb; }
  }
  __syncthreads();                                   // B3

  const unsigned bin   = 0x3F00u | sel[0];           // full bits[31:16] of bin
  const unsigned kRem2 = kRem - sel[1];
  const unsigned m     = sel[2];
  const bool slow = (n0 > (unsigned)TG_CAP) || (n0 < k + 32u) || (c2v >= k) ||
                    (bin < TG_BING) || (m > 64u) || (kRem2 == 0u) || (kRem2 > m);

  if (slow) {
    // ---- general path (proven r3-r6): full-row keyed radix + tie bitmap ----
    unsigned gk[16];
#pragma unroll
    for (int e = 0; e < 16; ++e) gk[e] = tg_key(tg_gelu(xv[e]));
    unsigned prefix = 0, kRemS = k;
#pragma unroll
    for (int ps = 0; ps < 4; ++ps) {
      const int shift = 24 - 8 * ps;
      __syncthreads();
      hist[0][tid] = 0; hist[1][tid] = 0; hist[2][tid] = 0; hist[3][tid] = 0;
      __syncthreads();
      const unsigned pmask = ps ? (0xFFFFFFFFu << (shift + 8)) : 0u;
#pragma unroll
      for (int e = 0; e < 16; ++e)
        if ((gk[e] & pmask) == prefix) atomicAdd(&hist[wv][(gk[e] >> shift) & 255], 1u);
      tg_pick_byte(hist, wtot, sel, kRemS, tid, lane, wv);
      prefix |= sel[0] << shift;
      kRemS  -= sel[1];
    }
    const unsigned Tg = prefix, kRemF = kRemS, cntEq = sel[2];
    const bool needTie = (cntEq != kRemF);
    if (needTie) {
      if (tid < 128) tieMask[tid] = 0;
      __syncthreads();
#pragma unroll
      for (int e = 0; e < 16; ++e)
        if (gk[e] == Tg) {
          unsigned s = (unsigned)((tid + (e >> 2) * TG_BLK) * 4 + (e & 3));
          atomicOr(&tieMask[s >> 5], 1u << (s & 31));
        }
      __syncthreads();
    }
#pragma unroll
    for (int c = 0; c < 4; ++c) {
      float rr[4];
#pragma unroll
      for (int j = 0; j < 4; ++j) {
        const int e = 4 * c + j;
        unsigned kk = gk[e];
        bool keep = kk > Tg;
        if (!keep && kk == Tg) {
          if (!needTie) keep = true;
          else {
            unsigned s = (unsigned)((tid + c * TG_BLK) * 4 + j);
            unsigned rank = __popc(tieMask[s >> 5] & ((1u << (s & 31)) - 1u));
            for (unsigned w = 0; w < (s >> 5); ++w) rank += __popc(tieMask[w]);
            keep = rank < kRemF;
          }
        }
        rr[j] = keep ? __uint_as_float(tg_dec(kk)) : 0.0f;
      }
      v4f o4 = { rr[0], rr[1], rr[2], rr[3] };
      __builtin_nontemporal_store(o4, reinterpret_cast<v4f*>(outr) + tid + c * TG_BLK);
    }
    return;
  }

  // ---- gather boundary-bin survivors (~6 expected, guarded <= 64) ----
  for (unsigned i = tid; i < nC; i += TG_BLK) {
    unsigned gb = ckey[i];
    if ((gb >> 16) == bin) {
      unsigned p = atomicAdd(&mCnt, 1u);
      if (p < 64u) { skey[p] = gb; scidx[p] = cidx[i]; scpos[p] = (unsigned short)i; }
    }
  }
  __syncthreads();                                   // B4

  // ---- wave 0: rank survivors (g desc, index asc), verdict into ckey ----
  if (wv == 0) {
    unsigned myk = (lane < (int)m) ? skey[lane] : 0u;
    unsigned myi = (lane < (int)m) ? (unsigned)scidx[lane] : 0xFFFFu;
    unsigned gt = 0, tr = 0;
    for (unsigned j = 0; j < m; ++j) {
      unsigned kj = __shfl(myk, (int)j, 64);
      unsigned ij = __shfl(myi, (int)j, 64);
      gt += (kj > myk) ? 1u : 0u;
      tr += (kj == myk && ij < myi) ? 1u : 0u;
    }
    if (lane < (int)m) ckey[scpos[lane]] = ((gt + tr) < kRem2) ? myk : 0u;
  }
  __syncthreads();                                   // B5

  // ---- per-thread verdict (sequential ckey reads) + nontemporal store ----
  const unsigned thr = bin << 16;
  unsigned p = base;
#pragma unroll
  for (int c = 0; c < 4; ++c) {
    float rr[4];
#pragma unroll
    for (int j = 0; j < 4; ++j) {
      const int e = 4 * c + j;
      float ov = 0.0f;
      if (candMask & (1u << e)) {
        unsigned gb = ckey[p++];
        if (gb >= thr) ov = __uint_as_float(gb);
      }
      rr[j] = ov;
    }
    v4f o4 = { rr[0], rr[1], rr[2], rr[3] };
    __builtin_nontemporal_store(o4, reinterpret_cast<v4f*>(outr) + tid + c * TG_BLK);
  }
}

extern "C" void kernel_launch(void* const* d_in, const int* in_sizes, int n_in,
                              void* d_out, int out_size, void* d_ws, size_t ws_size,
                              hipStream_t stream) {
  const float* x = (const float*)d_in[0];
  const int* kp  = (const int*)d_in[1];
  float* out     = (float*)d_out;
  int rows = in_sizes[0] / TG_D;
  topk_gelu_kernel<<<rows, TG_BLK, 0, stream>>>(x, kp, out);
}